// Round 9
// baseline (145.384 us; speedup 1.0000x reference)
//
#include <hip/hip_runtime.h>

// Predictor_8924942041234 — 2-hop rule grounding over a KG, ONE dispatch.
// x0 one-hot -> hop1 frontier (~640 matching edges); rules collapse to
// W[r1][r2] (24x24); hop2 hits ~3% of edges. Single plain launch with a
// fence-free software grid barrier (2 phases of one counter).
//
// COHERENCE LESSONS (rounds 5-8, all measured):
//  * agent-scope fences: buffer_wbl2/inv = 4MiB L2 tag walks. 115us/50us. NO.
//  * plain stores + remote MALL atomicAdd on same lines: diverging copies,
//    kernel-end clobber (r7 fail). NO.
//  * coherent (sc1) bulk stores: ~350 GB/s (no line write-combining) — 30us
//    for 10MB (r8). NO for bulk data.
//  => Design rule: `out` is written ONLY by plain full-BW stores, exactly
//     once, after all cross-block data has moved through the coherence point
//     via (cheap, sparse) agent-scope atomics.
//
// Structure: B1 builds chain1 (hop1 edges keyed by tail) + writes mask=1.
// Barrier. B2 probes chain1 per edge, pushes ~7K {b,w} records into chain2
// keyed by hop2 tail. Barrier. C: each block gathers 40 entities' chains
// into LDS and plain-stores score = bias + acc. Poison-safe: headptr stores
// idx+1 (>=1), poison/zero reads <=0 -> empty; barrier counter handshake via
// MAGIC flag; recCnt zeroed before MAGIC. Barrier deadlock-free: 512 blocks
// = 2/CU x 256 CUs co-resident via __launch_bounds__(256,2); bounded spins.

namespace {
constexpr int kNEnt    = 20000;
constexpr int kNRel    = 24;
constexpr int kNEdge   = 200000;
constexpr int kBatch   = 64;
constexpr int kNRules  = 32;
constexpr int kWSz     = kNRel * kNRel;          // 576
constexpr int kBlocks  = 512;                    // 2 blocks/CU -> co-resident
constexpr int kT       = 256;
constexpr int kGT      = kBlocks * kT;           // 131072
constexpr int kMask4   = kBatch * kNEnt / 4;     // 320000 float4 (mask part)
constexpr int kCE      = 40;                     // entities per block, phase C
constexpr int kRecCap  = 65535;                  // record cap (expect ~7K)
constexpr unsigned kMagic     = 0x5EEDF00Du;
constexpr unsigned kSpinLimit = 1u << 20;        // hang guard, never hit
// ws layout (bytes):
//   0        headptr1[20000] int  (e+1 chain1 head by hop1 tail; NO init)
//   81920    barA (barrier counter; phase1 waits 512, phase2 waits 1024)
//   82048    barB (init-magic flag)
//   82176    recCnt (record allocator)
//   90112    nodeNext1[200000] u32 ((prev or 0) | r1<<24)
//   983040   nodeBm1[200000] u64  (query bits matching hop1 edge e)
//   2583040  headptr2[20000] int  (rec+1 chain2 head by hop2 tail; NO init)
//   2663040  recMeta[65536] u32   (b | next<<6 ; next = rec+1 or 0)
//   2926080  recW[65536] f32
}

#define AGENT_LD(p)     __hip_atomic_load((p), __ATOMIC_RELAXED, __HIP_MEMORY_SCOPE_AGENT)
#define AGENT_ST(p, v)  __hip_atomic_store((p), (v), __ATOMIC_RELAXED, __HIP_MEMORY_SCOPE_AGENT)
#define AGENT_XCHG(p,v) __hip_atomic_exchange((p), (v), __ATOMIC_RELAXED, __HIP_MEMORY_SCOPE_AGENT)
#define AGENT_ADD(p, v) __hip_atomic_fetch_add((p), (v), __ATOMIC_RELAXED, __HIP_MEMORY_SCOPE_AGENT)

__global__ void __launch_bounds__(kT, 2) k_fused(
        const int* __restrict__ all_h,
        const int* __restrict__ rem,
        const int* __restrict__ eh,
        const int* __restrict__ er,
        const int* __restrict__ et,
        const int* __restrict__ rb,
        const float* __restrict__ rw,
        const float* __restrict__ bias,
        float* __restrict__ out,
        int* __restrict__ headptr1,
        unsigned* __restrict__ barA,
        unsigned* __restrict__ barB,
        unsigned* __restrict__ recCnt,
        unsigned* __restrict__ nodeNext1,
        unsigned long long* __restrict__ nodeBm1,
        int* __restrict__ headptr2,
        unsigned* __restrict__ recMeta,
        float* __restrict__ recW) {
    __shared__ int   sh[kBatch];
    __shared__ int   srem[kBatch];
    __shared__ float sW[kWSz];
    __shared__ float accL[kBatch * kCE];         // 10240 B
    const int t = threadIdx.x;

    // counters init handshake: zero barA/recCnt, drain, then publish MAGIC
    if (blockIdx.x == 0 && t == 0) {
        AGENT_ST(barA, 0u);
        AGENT_ST(recCnt, 0u);
        __builtin_amdgcn_s_waitcnt(0);       // both acked before MAGIC visible
        AGENT_ST(barB, kMagic);
    }

    if (t < kBatch) sh[t] = all_h[t];
    else if (t < 2 * kBatch) srem[t - kBatch] = rem[t - kBatch];
    for (int i = t; i < kWSz; i += kT) sW[i] = 0.f;
    __syncthreads();
    if (t < kNRules)
        atomicAdd(&sW[rb[2 * t] * kNRel + rb[2 * t + 1]], rw[t]);
    __syncthreads();                             // sW ready for B2

    const int gid = blockIdx.x * kT + t;

    // ---- Phase B1a: mask[b,:] = 1 — plain full-BW stores (these lines are
    //      never touched by atomics; score is written only in phase C) ----
    {
        float4* mask4 = (float4*)(out + kBatch * kNEnt);
        const float4 one4 = make_float4(1.f, 1.f, 1.f, 1.f);
        for (int i = gid; i < kMask4; i += kGT) mask4[i] = one4;
    }

    // ---- Phase B1b: hop1 chain1 build (coherent writes) + reg preload ----
    int  ph[2], pr[2], pt[2];
    bool pok[2];
#pragma unroll
    for (int j = 0; j < 2; j++) {
        int e = gid + j * kGT;
        pok[j] = false;
        ph[j] = 0; pr[j] = 0; pt[j] = 0;
        if (e < kNEdge) {
            int h  = eh[e];
            int r  = er[e];
            int tl = et[e];
            bool removed = false;
            for (int i = 0; i < kBatch; i++) removed |= (srem[i] == e);
            if (!removed) {
                pok[j] = true; ph[j] = h; pr[j] = r; pt[j] = tl;
                unsigned long long bm = 0ull;
                for (int b = 0; b < kBatch; b++)
                    bm |= (unsigned long long)(sh[b] == h) << b;
                if (bm) {
                    int old = AGENT_XCHG(&headptr1[tl], e + 1);   // e+1 >= 1
                    AGENT_ST(&nodeNext1[e], ((old <= 0) ? 0u : (unsigned)old)
                                            | ((unsigned)r << 24));
                    AGENT_ST(&nodeBm1[e], bm);
                }
            }
        }
    }

    // ---- barrier 1 (fence-free; syncthreads' vmcnt drain is the release) --
    __syncthreads();
    if (t == 0) {
        unsigned tries = 0;
        while (AGENT_LD(barB) != kMagic && ++tries < kSpinLimit)
            __builtin_amdgcn_s_sleep(1);
        AGENT_ADD(barA, 1u);
        tries = 0;
        while (AGENT_LD(barA) < (unsigned)kBlocks && ++tries < kSpinLimit)
            __builtin_amdgcn_s_sleep(1);
    }
    __syncthreads();

    // ---- Phase B2: probe chain1 per edge, push {b,w} records on chain2 ----
#pragma unroll
    for (int j = 0; j < 2; j++) {
        if (!pok[j]) continue;
        int p = AGENT_LD(&headptr1[ph[j]]);
        if (p <= 0) continue;                    // ~97% of edges exit here
        int r2 = pr[j];
        int t2 = pt[j];
        while (p > 0) {
            int e1 = p - 1;
            unsigned nx           = AGENT_LD(&nodeNext1[e1]);
            unsigned long long bm = AGENT_LD(&nodeBm1[e1]);
            float w = sW[((nx >> 24) & 31u) * kNRel + r2];
            while (bm) {
                int b = __ffsll(bm) - 1;
                bm &= bm - 1;
                unsigned pos = AGENT_ADD(recCnt, 1u);
                if (pos < (unsigned)kRecCap) {
                    int old = AGENT_XCHG(&headptr2[t2], (int)pos + 1);
                    AGENT_ST(&recMeta[pos],
                             (unsigned)b | ((unsigned)((old <= 0) ? 0 : old) << 6));
                    AGENT_ST(&recW[pos], w);
                }
            }
            p = (int)(nx & 0xFFFFFFu);
        }
    }

    // ---- barrier 2 (same counter, target 2*kBlocks) ----
    __syncthreads();
    if (t == 0) {
        AGENT_ADD(barA, 1u);
        unsigned tries = 0;
        while (AGENT_LD(barA) < 2u * kBlocks && ++tries < kSpinLimit)
            __builtin_amdgcn_s_sleep(1);
    }
    __syncthreads();

    // ---- Phase C: gather chain2 for this block's 40 entities, then
    //      plain-store score = bias + acc (sole writer, full BW) ----
    const int base = blockIdx.x * kCE;
    if (base < kNEnt) {
        for (int i = t; i < kBatch * kCE; i += kT) accL[i] = 0.f;
        __syncthreads();
        if (t < kCE) {
            int n = base + t;
            if (n < kNEnt) {
                int p = AGENT_LD(&headptr2[n]);
                while (p > 0) {
                    unsigned m = AGENT_LD(&recMeta[p - 1]);
                    float    w = AGENT_LD(&recW[p - 1]);
                    accL[(m & 63u) * kCE + t] += w;   // thread owns entity t
                    p = (int)(m >> 6);
                }
            }
        }
        __syncthreads();
        for (int i = t; i < kBatch * kCE; i += kT) {
            int b = i / kCE;
            int j = i - b * kCE;
            int n = base + j;
            if (n < kNEnt)
                out[b * kNEnt + n] = bias[n] + accL[i];
        }
    }
}

extern "C" void kernel_launch(void* const* d_in, const int* in_sizes, int n_in,
                              void* d_out, int out_size, void* d_ws, size_t ws_size,
                              hipStream_t stream) {
    const int*   all_h = (const int*)d_in[0];
    // d_in[1] = all_r (unused by the reference)
    const int*   rem   = (const int*)d_in[2];
    const int*   eh    = (const int*)d_in[3];
    const int*   er    = (const int*)d_in[4];
    const int*   et    = (const int*)d_in[5];
    const int*   rb    = (const int*)d_in[6];
    const float* rw    = (const float*)d_in[7];
    const float* bias  = (const float*)d_in[8];
    float* out = (float*)d_out;

    char* ws = (char*)d_ws;
    int*                headptr1  = (int*)(ws + 0);
    unsigned*           barA      = (unsigned*)(ws + 81920);
    unsigned*           barB      = (unsigned*)(ws + 82048);
    unsigned*           recCnt    = (unsigned*)(ws + 82176);
    unsigned*           nodeNext1 = (unsigned*)(ws + 90112);
    unsigned long long* nodeBm1   = (unsigned long long*)(ws + 983040);
    int*                headptr2  = (int*)(ws + 2583040);
    unsigned*           recMeta   = (unsigned*)(ws + 2663040);
    float*              recW      = (float*)(ws + 2926080);

    hipLaunchKernelGGL(k_fused, dim3(kBlocks), dim3(kT), 0, stream,
                       all_h, rem, eh, er, et, rb, rw, bias, out,
                       headptr1, barA, barB, recCnt,
                       nodeNext1, nodeBm1, headptr2, recMeta, recW);
}